// Round 19
// baseline (1203.618 us; speedup 1.0000x reference)
//
#include <hip/hip_runtime.h>

// Problem constants (from reference)
constexpr int B_ = 8;
constexpr int N_ = 16384;
constexpr int NG = 512;     // NUM_GROUPS
constexpr int GS = 32;      // GROUP_SIZE
constexpr int KORIG = 160;  // K_ORIGINAL = 5*GROUP_SIZE
constexpr int TPB = 1024;   // 16 waves per block
constexpr int PPT = 16;     // fps: points per thread (8 pk pairs), contiguous
constexpr int NFPS = 8;     // fps blocks (one per batch)
constexpr int NGRPBLK = 256;  // group blocks: 16 waves x 256 = 4096 groups
#define R2 0.04f
#define RADIUS 0.2f

typedef __attribute__((ext_vector_type(2))) float f32x2;

__device__ __forceinline__ unsigned f32_ord(float f) {
  unsigned u = __float_as_uint(f);
  return (u & 0x80000000u) ? ~u : (u | 0x80000000u);
}

// packed f32 math: IEEE-identical per component to scalar v_add/v_mul
__device__ __forceinline__ f32x2 pk_add(f32x2 a, f32x2 b) {
  f32x2 d;
  asm("v_pk_add_f32 %0, %1, %2" : "=v"(d) : "v"(a), "v"(b));
  return d;
}
__device__ __forceinline__ f32x2 pk_mul(f32x2 a, f32x2 b) {
  f32x2 d;
  asm("v_pk_mul_f32 %0, %1, %2" : "=v"(d) : "v"(a), "v"(b));
  return d;
}

template <int CTRL>
__device__ __forceinline__ float dpp_fmax(float v) {
  int o = __builtin_amdgcn_update_dpp(0, __float_as_int(v), CTRL, 0xF, 0xF, true);
  return fmaxf(v, __int_as_float(o));
}
// full 64-lane max
__device__ __forceinline__ float wave_fmax(float v) {
  v = dpp_fmax<0xB1>(v);   // quad_perm xor1
  v = dpp_fmax<0x4E>(v);   // quad_perm xor2
  v = dpp_fmax<0x141>(v);  // row_half_mirror
  v = dpp_fmax<0x140>(v);  // row_mirror
  v = fmaxf(v, __int_as_float(__builtin_amdgcn_ds_swizzle(__float_as_int(v), 0x401F)));  // xor16
  v = fmaxf(v, __shfl_xor(v, 32, 64));  // xor32
  return v;
}
// max within each 16-lane group (lanes g*16..g*16+15 hold the 16 wave partials)
__device__ __forceinline__ float group16_fmax(float v) {
  v = dpp_fmax<0xB1>(v);
  v = dpp_fmax<0x4E>(v);
  v = dpp_fmax<0x141>(v);
  v = dpp_fmax<0x140>(v);
  return v;
}

// re-arm progress counters every launch (graph-replay safe)
__global__ void prog_init(unsigned* prog) { prog[threadIdx.x] = 0u; }

// ---------------- Fused kernel ----------------
// Blocks 0..7: r16's FPS verbatim (16 waves, single barrier, pk math,
// s_load winner) + per-iteration release publish of prog[b] = #centers done.
// Blocks 8..263: 16 waves each, one wave per (batch,group); each wave
// s_sleep-polls prog[b] > g (acquire, agent scope), then runs ball query +
// energy top-k + gather on its private LDS slice — group work overlaps the
// FPS tail instead of serializing after it.
// Deadlock-free: 264 blocks x 16 waves = 4224 waves < 8192 chip capacity,
// so every block is co-resident regardless of dispatch order.
__global__ __attribute__((amdgpu_flat_work_group_size(1024, 1024),
                          amdgpu_waves_per_eu(4, 4)))
void fused_kernel(const float4* __restrict__ p4,
                  const int* __restrict__ lengths,
                  float* __restrict__ centers,
                  float4* __restrict__ outg,
                  unsigned* __restrict__ prog) {
#pragma clang fp contract(off)
  const int t = threadIdx.x;
  const int lane = t & 63;
  const int wid = t >> 6;

  __shared__ float pubf[2][16];        // fps: per-wave max, parity dbuf
  __shared__ int pubi[2][16];          // fps: per-wave winner index, parity dbuf
  __shared__ int candw[16][KORIG];     // group: per-wave candidate slices

  if (blockIdx.x >= NFPS) {
    // ================= group path: one wave per (batch, group) =============
    const int G = ((int)blockIdx.x - NFPS) * 16 + wid;
    const int b = G >> 9;
    const int g = G & 511;
    const float4* bp = p4 + (size_t)b * N_;
    const int len = lengths[b];

    // wait until center g is published (acquire pairs with fps release)
    while (__hip_atomic_load(&prog[b], __ATOMIC_ACQUIRE,
                             __HIP_MEMORY_SCOPE_AGENT) <= (unsigned)g) {
      __builtin_amdgcn_s_sleep(32);
    }
    const unsigned* cbits = (const unsigned*)(centers + (size_t)(b * NG + g) * 3);
    const float cx = __uint_as_float(__hip_atomic_load(
        &cbits[0], __ATOMIC_RELAXED, __HIP_MEMORY_SCOPE_AGENT));
    const float cy = __uint_as_float(__hip_atomic_load(
        &cbits[1], __ATOMIC_RELAXED, __HIP_MEMORY_SCOPE_AGENT));
    const float cz = __uint_as_float(__hip_atomic_load(
        &cbits[2], __ATOMIC_RELAXED, __HIP_MEMORY_SCOPE_AGENT));

    int* cand = candw[wid];
    int M = 0;  // wave-uniform running in-ball count
    for (int cb = 0; cb < N_ && M < KORIG; cb += 256) {
#pragma unroll
      for (int q = 0; q < 4; ++q) {
        const int i = cb + q * 64 + lane;
        float4 p = bp[i];
        float dx = p.x - cx;
        float dy = p.y - cy;
        float dz = p.z - cz;
        float d2 = dx * dx + dy * dy + dz * dz;  // contract OFF
        const bool pred = (i < len) && (d2 < R2);
        unsigned long long mb = __ballot(pred);
        if (pred) {
          int pos = M + (int)__popcll(mb & ((1ull << lane) - 1ull));
          if (pos < KORIG) cand[pos] = i;  // first-160-by-index semantics
        }
        M += (int)__popcll(mb);
      }
    }
    if (M > KORIG) M = KORIG;
    // wave-private LDS: compiler's in-wave lgkmcnt ordering suffices (no barrier)

    // keys: (energy desc, index asc) -> ascending u64
    const unsigned long long SENT = ~0ull;
    unsigned long long key0 = SENT, key1 = SENT, key2 = SENT;
    {
      int c0 = lane, c1 = lane + 64, c2 = lane + 128;
      if (c0 < M) { int i = cand[c0]; key0 = ((unsigned long long)(~f32_ord(bp[i].w)) << 32) | (unsigned)i; }
      if (c1 < M) { int i = cand[c1]; key1 = ((unsigned long long)(~f32_ord(bp[i].w)) << 32) | (unsigned)i; }
      if (c2 < M) { int i = cand[c2]; key2 = ((unsigned long long)(~f32_ord(bp[i].w)) << 32) | (unsigned)i; }
    }

    int mysel = -1;  // lane j holds the j-th selected index
    for (int j = 0; j < GS; ++j) {
      unsigned long long kmin = key0 < key1 ? key0 : key1;
      if (key2 < kmin) kmin = key2;
#pragma unroll
      for (int off = 32; off > 0; off >>= 1) {
        unsigned long long o = __shfl_xor(kmin, off, 64);
        if (o < kmin) kmin = o;
      }
      if (kmin == SENT) break;  // fewer than 32 candidates; rest stay -1
      if (lane == j) mysel = (int)(unsigned)kmin;
      if (key0 == kmin) key0 = SENT;
      if (key1 == kmin) key1 = SENT;
      if (key2 == kmin) key2 = SENT;
    }

    const int first = __shfl(mysel, 0, 64);  // highest-energy candidate (or -1)
    if (lane < GS) {
      int idx = (mysel < 0) ? first : mysel;  // reference: -1 -> idx[:, :, :1]
      float4 o;
      if (idx >= 0) {
        float4 p = bp[idx];
        o.x = (p.x - cx) / RADIUS;
        o.y = (p.y - cy) / RADIUS;
        o.z = (p.z - cz) / RADIUS;
        o.w = p.w / RADIUS;
      } else {
        o.x = (0.0f - cx) / RADIUS;
        o.y = (0.0f - cy) / RADIUS;
        o.z = (0.0f - cz) / RADIUS;
        o.w = 0.0f;
      }
      outg[(size_t)G * GS + lane] = o;
    }
    return;
  }

  // ================= fps path (r16 verbatim + prog publish) ================
  const int b = blockIdx.x;
  const int len = lengths[b];
  const float4* bp = p4 + (size_t)b * N_;
  const float INF = __builtin_inff();
  unsigned* cOut = (unsigned*)(centers + (size_t)b * NG * 3);

  f32x2 x2[8], y2[8], z2[8], m2[8];
#pragma unroll
  for (int p = 0; p < 8; ++p) {
    const int i0 = t * PPT + 2 * p;
    float4 a = bp[i0];       // per-thread contiguous 256B: full line use
    float4 c = bp[i0 + 1];
    x2[p] = (f32x2){a.x, c.x};
    y2[p] = (f32x2){a.y, c.y};
    z2[p] = (f32x2){a.z, c.z};
    m2[p].x = (i0 < len) ? INF : -INF;
    m2[p].y = (i0 + 1 < len) ? INF : -INF;
  }

  float4 c0 = bp[0];  // reference scan starts at cur=0
  float cx = c0.x, cy = c0.y, cz = c0.z;
  if (t == 0) {
    __hip_atomic_store(&cOut[0], __float_as_uint(cx), __ATOMIC_RELAXED, __HIP_MEMORY_SCOPE_AGENT);
    __hip_atomic_store(&cOut[1], __float_as_uint(cy), __ATOMIC_RELAXED, __HIP_MEMORY_SCOPE_AGENT);
    __hip_atomic_store(&cOut[2], __float_as_uint(cz), __ATOMIC_RELAXED, __HIP_MEMORY_SCOPE_AGENT);
    __hip_atomic_store(&prog[b], 1u, __ATOMIC_RELEASE, __HIP_MEMORY_SCOPE_AGENT);
  }

  for (int k = 0; k < NG - 1; ++k) {
    // --- mindist update: all-register pk math, exact reference rounding ---
    const f32x2 mcx = {-cx, -cx};
    const f32x2 mcy = {-cy, -cy};
    const f32x2 mcz = {-cz, -cz};
#pragma unroll
    for (int p = 0; p < 8; ++p) {
      f32x2 xx = pk_add(x2[p], mcx);   // x - cx (as x + (-cx), exact)
      f32x2 yy = pk_add(y2[p], mcy);
      f32x2 zz = pk_add(z2[p], mcz);
      f32x2 xs = pk_mul(xx, xx);
      f32x2 ys = pk_mul(yy, yy);
      f32x2 s1 = pk_add(xs, ys);       // dx2 + dy2
      f32x2 zs = pk_mul(zz, zz);
      f32x2 d2 = pk_add(s1, zs);       // (dx2+dy2) + dz2 = np.sum order
      m2[p].x = fminf(m2[p].x, d2.x);
      m2[p].y = fminf(m2[p].y, d2.y);
    }
    // --- thread max tree over 8 pair-maxes (levels kept for descent) ---
    float pm[8];
#pragma unroll
    for (int i = 0; i < 8; ++i) pm[i] = fmaxf(m2[i].x, m2[i].y);
    float b4[4];
#pragma unroll
    for (int i = 0; i < 4; ++i) b4[i] = fmaxf(pm[2 * i], pm[2 * i + 1]);
    float b2[2] = {fmaxf(b4[0], b4[1]), fmaxf(b4[2], b4[3])};
    const float sm = fmaxf(b2[0], b2[1]);

    // --- leftmost-attaining pair via 3-level descent + half bit ---
    const bool i1 = (b2[0] != sm);                   // 1 -> pairs 4..7
    const float aL4 = i1 ? b4[2] : b4[0];
    const bool i2 = (aL4 != sm);
    const float pmL = i1 ? (i2 ? pm[6] : pm[4]) : (i2 ? pm[2] : pm[0]);
    const bool i3 = (pmL != sm);
    const int jp = ((int)i1 << 2) | ((int)i2 << 1) | (int)i3;
    const float mlo =
        i1 ? (i2 ? (i3 ? m2[7].x : m2[6].x) : (i3 ? m2[5].x : m2[4].x))
           : (i2 ? (i3 ? m2[3].x : m2[2].x) : (i3 ? m2[1].x : m2[0].x));
    const bool blo = (mlo != sm);  // false -> low half attains (first index)
    const int gidx = t * PPT + jp * 2 + (int)blo;

    // --- wave max + first-lane tie-break; publish (value, index) ---
    const float wmax = wave_fmax(sm);
    const unsigned long long att = __ballot(sm == wmax);
    const int wl = __ffsll(att) - 1;  // lowest lane = lowest index
    if (lane == wl) {
      pubf[k & 1][wid] = wmax;
      pubi[k & 1][wid] = gidx;
    }
    __syncthreads();  // the only barrier; parity slots make one enough

    // --- all waves: read 16 partials, reduce, broadcast, s_load winner ---
    const float pw = pubf[k & 1][lane & 15];
    const int pi = pubi[k & 1][lane & 15];
    const float kmax = group16_fmax(pw);
    const unsigned long long bal = __ballot(pw == kmax);
    const int grp = lane & 48;
    const int src = grp + (__ffsll((bal >> grp) & 0xFFFFull) - 1);  // lowest wave
    const int gsel = __shfl(pi, src, 64);
    const int snxt = __builtin_amdgcn_readfirstlane(gsel);  // SGPR -> s_load
    const float4 c = bp[snxt];                              // wave-uniform, L2-hot
    cx = c.x; cy = c.y; cz = c.z;

    if (t == 0) {
      unsigned* co = cOut + (size_t)(k + 1) * 3;
      __hip_atomic_store(&co[0], __float_as_uint(cx), __ATOMIC_RELAXED, __HIP_MEMORY_SCOPE_AGENT);
      __hip_atomic_store(&co[1], __float_as_uint(cy), __ATOMIC_RELAXED, __HIP_MEMORY_SCOPE_AGENT);
      __hip_atomic_store(&co[2], __float_as_uint(cz), __ATOMIC_RELAXED, __HIP_MEMORY_SCOPE_AGENT);
      __hip_atomic_store(&prog[b], (unsigned)(k + 2), __ATOMIC_RELEASE, __HIP_MEMORY_SCOPE_AGENT);
    }
  }
}

extern "C" void kernel_launch(void* const* d_in, const int* in_sizes, int n_in,
                              void* d_out, int out_size, void* d_ws, size_t ws_size,
                              hipStream_t stream) {
  const float4* pts = (const float4*)d_in[0];
  const int* lengths = (const int*)d_in[1];
  float* out = (float*)d_out;
  // out layout: groups (8,512,32,4) flat, then centers (8,512,3) flat
  float* centers = out + (size_t)B_ * NG * GS * 4;
  float4* groups = (float4*)out;
  unsigned* prog = (unsigned*)d_ws;  // 8 progress counters

  prog_init<<<1, B_, 0, stream>>>(prog);
  fused_kernel<<<NFPS + NGRPBLK, TPB, 0, stream>>>(pts, lengths, centers,
                                                   groups, prog);
}

// Round 20
// 891.482 us; speedup vs baseline: 1.3501x; 1.3501x over previous
//
#include <hip/hip_runtime.h>

// Problem constants (from reference)
constexpr int B_ = 8;
constexpr int N_ = 16384;
constexpr int NG = 512;     // NUM_GROUPS
constexpr int GS = 32;      // GROUP_SIZE
constexpr int KORIG = 160;  // K_ORIGINAL = 5*GROUP_SIZE
constexpr int TPB = 512;    // fps threads: 8 waves, 2 per SIMD
constexpr int PPT = 32;     // points per thread (16 pk pairs), contiguous
#define R2 0.04f
#define RADIUS 0.2f

typedef __attribute__((ext_vector_type(2))) float f32x2;

__device__ __forceinline__ unsigned f32_ord(float f) {
  unsigned u = __float_as_uint(f);
  return (u & 0x80000000u) ? ~u : (u | 0x80000000u);
}

// packed f32 math: IEEE-identical per component to scalar v_add/v_mul
__device__ __forceinline__ f32x2 pk_add(f32x2 a, f32x2 b) {
  f32x2 d;
  asm("v_pk_add_f32 %0, %1, %2" : "=v"(d) : "v"(a), "v"(b));
  return d;
}
__device__ __forceinline__ f32x2 pk_mul(f32x2 a, f32x2 b) {
  f32x2 d;
  asm("v_pk_mul_f32 %0, %1, %2" : "=v"(d) : "v"(a), "v"(b));
  return d;
}

template <int CTRL>
__device__ __forceinline__ float dpp_fmax(float v) {
  int o = __builtin_amdgcn_update_dpp(0, __float_as_int(v), CTRL, 0xF, 0xF, true);
  return fmaxf(v, __int_as_float(o));
}
// full 64-lane max
__device__ __forceinline__ float wave_fmax(float v) {
  v = dpp_fmax<0xB1>(v);   // quad_perm xor1
  v = dpp_fmax<0x4E>(v);   // quad_perm xor2
  v = dpp_fmax<0x141>(v);  // row_half_mirror
  v = dpp_fmax<0x140>(v);  // row_mirror
  v = fmaxf(v, __int_as_float(__builtin_amdgcn_ds_swizzle(__float_as_int(v), 0x401F)));  // xor16
  v = fmaxf(v, __shfl_xor(v, 32, 64));  // xor32
  return v;
}
// max within each 8-lane group (lanes 8g..8g+7 hold the 8 wave partials)
__device__ __forceinline__ float group8_fmax(float v) {
  v = dpp_fmax<0xB1>(v);
  v = dpp_fmax<0x4E>(v);
  v = dpp_fmax<0x141>(v);
  return v;
}

// ---------------- Kernel 1: farthest point sampling (r13, session best) -----
// One block per batch, 512 threads (8 waves, 2/SIMD); thread t owns points
// [32t,32t+32) CONTIGUOUS (tie-break = wave, lane, pair, half = index order).
// All-register pk math; single barrier/iter (parity publish slots);
// DPP reduces; uniform s_load of winner coords.
// 19-round ablation result: per-iteration time is a latency SUM of
// {issue, wave-reduce, barrier, LDS publish round-trip, winner load} —
// each term individually minimized; VALU-halving/barrier-removal/LDS-removal/
// fusion all within ±8% or regressive. This config is the measured optimum.
__global__ __attribute__((amdgpu_flat_work_group_size(512, 512),
                          amdgpu_waves_per_eu(2, 2)))
void fps_kernel(const float4* __restrict__ p4,
                const int* __restrict__ lengths,
                float* __restrict__ centers) {
#pragma clang fp contract(off)
  const int b = blockIdx.x;
  const int t = threadIdx.x;
  const int lane = t & 63;
  const int wid = t >> 6;
  const int len = lengths[b];
  const float4* bp = p4 + (size_t)b * N_;
  const float INF = __builtin_inff();

  __shared__ float pubf[2][8];  // per-wave max, parity dbuf
  __shared__ int pubi[2][8];    // per-wave winner global index, parity dbuf

  f32x2 x2[16], y2[16], z2[16], m2[16];
#pragma unroll
  for (int p = 0; p < 16; ++p) {
    const int i0 = t * PPT + 2 * p;
    float4 a = bp[i0];       // per-thread contiguous 512B: full line use
    float4 c = bp[i0 + 1];
    x2[p] = (f32x2){a.x, c.x};
    y2[p] = (f32x2){a.y, c.y};
    z2[p] = (f32x2){a.z, c.z};
    m2[p].x = (i0 < len) ? INF : -INF;
    m2[p].y = (i0 + 1 < len) ? INF : -INF;
  }

  float4 c0 = bp[0];  // reference scan starts at cur=0
  float cx = c0.x, cy = c0.y, cz = c0.z;
  if (t == 0) {
    size_t o = (size_t)b * NG * 3;
    centers[o] = cx; centers[o + 1] = cy; centers[o + 2] = cz;
  }

  for (int k = 0; k < NG - 1; ++k) {
    // --- mindist update: all-register pk math, exact reference rounding ---
    const f32x2 mcx = {-cx, -cx};
    const f32x2 mcy = {-cy, -cy};
    const f32x2 mcz = {-cz, -cz};
#pragma unroll
    for (int p = 0; p < 16; ++p) {
      f32x2 xx = pk_add(x2[p], mcx);   // x - cx (as x + (-cx), exact)
      f32x2 yy = pk_add(y2[p], mcy);
      f32x2 zz = pk_add(z2[p], mcz);
      f32x2 xs = pk_mul(xx, xx);
      f32x2 ys = pk_mul(yy, yy);
      f32x2 s1 = pk_add(xs, ys);       // dx2 + dy2
      f32x2 zs = pk_mul(zz, zz);
      f32x2 d2 = pk_add(s1, zs);       // (dx2+dy2) + dz2 = np.sum order
      m2[p].x = fminf(m2[p].x, d2.x);
      m2[p].y = fminf(m2[p].y, d2.y);
    }
    // --- thread max tree over 16 pair-maxes (levels kept for descent) ---
    float pm[16];
#pragma unroll
    for (int i = 0; i < 16; ++i) pm[i] = fmaxf(m2[i].x, m2[i].y);
    float b8[8];
#pragma unroll
    for (int i = 0; i < 8; ++i) b8[i] = fmaxf(pm[2 * i], pm[2 * i + 1]);
    float b4[4];
#pragma unroll
    for (int i = 0; i < 4; ++i) b4[i] = fmaxf(b8[2 * i], b8[2 * i + 1]);
    float b2[2] = {fmaxf(b4[0], b4[1]), fmaxf(b4[2], b4[3])};
    const float sm = fmaxf(b2[0], b2[1]);

    // --- leftmost-attaining pair via 4-level descent + half bit ---
    const bool i1 = (b2[0] != sm);
    const float aL4 = i1 ? b4[2] : b4[0];
    const bool i2 = (aL4 != sm);
    const float aL8 = i1 ? (i2 ? b8[6] : b8[4]) : (i2 ? b8[2] : b8[0]);
    const bool i3 = (aL8 != sm);
    const float pmL = i1 ? (i2 ? (i3 ? pm[14] : pm[12]) : (i3 ? pm[10] : pm[8]))
                         : (i2 ? (i3 ? pm[6] : pm[4]) : (i3 ? pm[2] : pm[0]));
    const bool i4 = (pmL != sm);
    const int jp = ((int)i1 << 3) | ((int)i2 << 2) | ((int)i3 << 1) | (int)i4;
    const float mlo =
        i1 ? (i2 ? (i3 ? (i4 ? m2[15].x : m2[14].x) : (i4 ? m2[13].x : m2[12].x))
                 : (i3 ? (i4 ? m2[11].x : m2[10].x) : (i4 ? m2[9].x : m2[8].x)))
           : (i2 ? (i3 ? (i4 ? m2[7].x : m2[6].x) : (i4 ? m2[5].x : m2[4].x))
                 : (i3 ? (i4 ? m2[3].x : m2[2].x) : (i4 ? m2[1].x : m2[0].x)));
    const bool blo = (mlo != sm);  // false -> low half attains (first index)
    const int gidx = t * PPT + jp * 2 + (int)blo;

    // --- wave max + first-lane tie-break; publish (value, index) ---
    const float wmax = wave_fmax(sm);
    const unsigned long long att = __ballot(sm == wmax);
    const int wl = __ffsll(att) - 1;  // lowest lane = lowest index
    if (lane == wl) {
      pubf[k & 1][wid] = wmax;
      pubi[k & 1][wid] = gidx;
    }
    __syncthreads();  // the only barrier; parity slots make one enough

    // --- all waves: read 8 partials, reduce, broadcast, s_load winner ---
    const float pw = pubf[k & 1][lane & 7];
    const int pi = pubi[k & 1][lane & 7];
    const float kmax = group8_fmax(pw);
    const unsigned long long bal = __ballot(pw == kmax);
    const int grp = lane & 56;
    const int src = grp + (__ffsll((bal >> grp) & 0xFFull) - 1);  // lowest wave wins
    const int gsel = __shfl(pi, src, 64);
    const int snxt = __builtin_amdgcn_readfirstlane(gsel);  // SGPR -> s_load
    const float4 c = bp[snxt];                              // wave-uniform, L2-hot
    cx = c.x; cy = c.y; cz = c.z;

    if (t == 0) {
      size_t o = ((size_t)b * NG + (k + 1)) * 3;
      centers[o] = cx; centers[o + 1] = cy; centers[o + 2] = cz;
    }
  }
}

// ---------------- Kernel 2: ball query + energy top-k + gather ----------------
// One wave per (batch, group). Ordered compaction of first 160 in-ball indices,
// then 32 rounds of min-key extraction = top_k by (energy desc, index asc).
__global__ __launch_bounds__(64) void group_kernel(const float4* __restrict__ p4,
                                                   const int* __restrict__ lengths,
                                                   const float* __restrict__ centers,
                                                   float4* __restrict__ outg) {
#pragma clang fp contract(off)
  const int gid = blockIdx.x;
  const int b = gid >> 9;
  const int lane = threadIdx.x;
  const int len = lengths[b];
  const float4* bp = p4 + (size_t)b * N_;
  const float cx = centers[(size_t)gid * 3 + 0];
  const float cy = centers[(size_t)gid * 3 + 1];
  const float cz = centers[(size_t)gid * 3 + 2];

  __shared__ int cand[KORIG];
  int M = 0;  // wave-uniform running in-ball count
  for (int cb = 0; cb < N_ && M < KORIG; cb += 256) {
#pragma unroll
    for (int q = 0; q < 4; ++q) {
      const int i = cb + q * 64 + lane;
      float4 p = bp[i];
      float dx = p.x - cx;
      float dy = p.y - cy;
      float dz = p.z - cz;
      float d2 = dx * dx + dy * dy + dz * dz;  // contract OFF
      const bool pred = (i < len) && (d2 < R2);
      unsigned long long mb = __ballot(pred);
      if (pred) {
        int pos = M + (int)__popcll(mb & ((1ull << lane) - 1ull));
        if (pos < KORIG) cand[pos] = i;  // first-160-by-index semantics
      }
      M += (int)__popcll(mb);
    }
  }
  if (M > KORIG) M = KORIG;
  __syncthreads();

  // keys: (energy desc, index asc) -> ascending u64
  const unsigned long long SENT = ~0ull;
  unsigned long long key0 = SENT, key1 = SENT, key2 = SENT;
  {
    int c0 = lane, c1 = lane + 64, c2 = lane + 128;
    if (c0 < M) { int i = cand[c0]; key0 = ((unsigned long long)(~f32_ord(bp[i].w)) << 32) | (unsigned)i; }
    if (c1 < M) { int i = cand[c1]; key1 = ((unsigned long long)(~f32_ord(bp[i].w)) << 32) | (unsigned)i; }
    if (c2 < M) { int i = cand[c2]; key2 = ((unsigned long long)(~f32_ord(bp[i].w)) << 32) | (unsigned)i; }
  }

  int mysel = -1;  // lane j holds the j-th selected index
  for (int j = 0; j < GS; ++j) {
    unsigned long long kmin = key0 < key1 ? key0 : key1;
    if (key2 < kmin) kmin = key2;
#pragma unroll
    for (int off = 32; off > 0; off >>= 1) {
      unsigned long long o = __shfl_xor(kmin, off, 64);
      if (o < kmin) kmin = o;
    }
    if (kmin == SENT) break;  // fewer than 32 candidates; rest stay -1
    if (lane == j) mysel = (int)(unsigned)kmin;
    if (key0 == kmin) key0 = SENT;
    if (key1 == kmin) key1 = SENT;
    if (key2 == kmin) key2 = SENT;
  }

  const int first = __shfl(mysel, 0, 64);  // highest-energy candidate (or -1 if empty)
  if (lane < GS) {
    int idx = (mysel < 0) ? first : mysel;  // reference: -1 -> idx[:, :, :1]
    float4 o;
    if (idx >= 0) {
      float4 p = bp[idx];
      o.x = (p.x - cx) / RADIUS;
      o.y = (p.y - cy) / RADIUS;
      o.z = (p.z - cz) / RADIUS;
      o.w = p.w / RADIUS;
    } else {
      // masked_gather gives 0, then (0 - center)/radius
      o.x = (0.0f - cx) / RADIUS;
      o.y = (0.0f - cy) / RADIUS;
      o.z = (0.0f - cz) / RADIUS;
      o.w = 0.0f;
    }
    outg[(size_t)gid * GS + lane] = o;
  }
}

extern "C" void kernel_launch(void* const* d_in, const int* in_sizes, int n_in,
                              void* d_out, int out_size, void* d_ws, size_t ws_size,
                              hipStream_t stream) {
  const float4* pts = (const float4*)d_in[0];
  const int* lengths = (const int*)d_in[1];
  float* out = (float*)d_out;
  // out layout: groups (8,512,32,4) flat, then centers (8,512,3) flat
  float* centers = out + (size_t)B_ * NG * GS * 4;
  float4* groups = (float4*)out;

  fps_kernel<<<B_, TPB, 0, stream>>>(pts, lengths, centers);
  group_kernel<<<B_ * NG, 64, 0, stream>>>(pts, lengths, centers, groups);
}